// Round 11
// baseline (256.493 us; speedup 1.0000x reference)
//
#include <hip/hip_runtime.h>
#include <math.h>

typedef unsigned short u16;
typedef __attribute__((ext_vector_type(8))) short short8;   // 8 bf16 operand frag (4 VGPRs)
typedef __attribute__((ext_vector_type(4))) float floatx4;  // 4 fp32 accum frag

#define LDS_AS(p) ((__attribute__((address_space(3))) void*)(p))
#define GLB_AS(p) ((const __attribute__((address_space(1))) void*)(p))

__device__ __forceinline__ u16 f2bf(float f) {
  unsigned int u = __float_as_uint(f);
  u += 0x7fffu + ((u >> 16) & 1u);          // round-to-nearest-even
  return (u16)(u >> 16);
}

__device__ __forceinline__ void gld16(const void* g, void* l) {
  // async global->LDS, 16B/lane, dest = wave-uniform base + lane*16
  __builtin_amdgcn_global_load_lds(GLB_AS(g), LDS_AS(l), 16, 0, 0);
}

__device__ __forceinline__ floatx4 mfma16(short8 a, short8 b, floatx4 c) {
  return __builtin_amdgcn_mfma_f32_16x16x32_bf16(a, b, c, 0, 0, 0);
}

// PANE CONVENTION: a pane is 512 u16 = [16 rows][32 cols] in MFMA lane order,
// element (lane,j) = src[row0 + (lane&15)][col0 + (lane>>4)*8 + j]. One
// gld16/store per pane is a single contiguous 1KB burst. Tensors:
//   qb,kb : [bh][chk16][nsub8][kk2][512]   kwt: [bh][chk16][m4][kst4][512]
//   vtb   : [bh][chk16][jd4][kst4][512]    Sb : [bh][chk16][nd4][kk2][512]

// ---------------------------------------------------------------- fused prep
__global__ void prep_kernel(const float* __restrict__ x, const float* __restrict__ Wq,
                            const float* __restrict__ Wk, const float* __restrict__ Wv,
                            const float* __restrict__ Wo, u16* __restrict__ xp,
                            u16* __restrict__ wqkvp, u16* __restrict__ wop,
                            float2* __restrict__ rtab) {
  int i = blockIdx.x * blockDim.x + threadIdx.x;
  const int str = gridDim.x * blockDim.x;
  for (; i < 3211264; i += str) {
    if (i < 3145728) {
      // one ushort4 (4 dest u16, same lane, j-half jh) per iteration
      int U; u16* d;
      const float* s;
      if (i < 2097152)      { U = i;           d = xp;    s = x;  }
      else if (i < 2883584) { U = i - 2097152; d = wqkvp; s = nullptr; }
      else                  { U = i - 2883584; d = wop;   s = Wo; }
      const int tile = U >> 12;            // 16-row tile
      const int kc   = (U >> 7) & 31;      // 32-col chunk
      const int lane = (U >> 1) & 63;
      const int jh   = U & 1;
      const int scol = kc * 32 + (lane >> 4) * 8 + jh * 4;
      int srow = tile * 16 + (lane & 15);
      if (s == nullptr) {                  // stacked Wq/Wk/Wv rows
        const int sel = srow >> 10;
        srow &= 1023;
        s = (sel == 0) ? Wq : (sel == 1) ? Wk : Wv;
      }
      float4 v = ((const float4*)s)[srow * 256 + (scol >> 2)];
      ushort4 o;
      o.x = f2bf(v.x); o.y = f2bf(v.y); o.z = f2bf(v.z); o.w = f2bf(v.w);
      ((ushort4*)d)[U] = o;
    } else {
      const int t = i - 3145728;              // 0..65535
      const int seq = t >> 5, dh = t & 31;
      const float freq = exp2f(-(float)dh * 0.42863594770f); // log2(1e4)/31
      float sn, cs;
      __sincosf((float)seq * freq, &sn, &cs);
      rtab[t] = make_float2(sn, cs);
    }
  }
}

// ---------------------------------------------------------------- QKV GEMM, 8-phase
// ROUND-11: faithful m201 8-phase port on pane layout. 256x256 tile, BK=64,
// 8 waves (wr=w>>2 M-half of 128 rows, wc=w&3 N-quarter of 64 cols),
// acc[8][4]. LDS 128 KB = 2 bufs x (A 32KB + B 32KB); pane-packed global ->
// LDS panes conflict-free + gload_lds-linear by construction (replaces
// st_16x32 swizzle; rule #21 satisfied via pre-packed global).
// Per K-tile t: b[4][2] ds_read at tile top; 4 phases q:
//   {ds_read a rows 2q..2q+1 (4xb128) -> stage one 16-pane unit (2 gld16)
//    -> [vmcnt(6) at q==3] -> BAR1 -> lgkmcnt(0)+sched_barrier
//    -> setprio(1) 16 MFMA setprio(0) -> BAR2}
// Stage units of tile T (2 gld16/wave each):
//   S_B0(T)@(T-2,q1) ct 0-7 | S_B1(T)@(T-2,q2) ct 8-15
//   S_A0(T)@(T-2,q3) rt {0-3,8-11} | S_A1(T)@(T-1,q0) rt {4-7,12-15}
// Ledger (checked per phase): every target region is register-consumed
// (lgkm(0) precedes that phase's MFMA precedes its BAR2) at least one barrier
// before the overwriting stage issues; tile-t reads are guarded by (t-1,q3)'s
// vmcnt(6)+BAR1 (3 units = 6 loads outstanding; in-order retirement m135).
// vmcnt at q3: t<=NT-3 -> 6; else 0 (epilogue drain). Barriers unconditional.
__global__ __launch_bounds__(512, 2)
void gemm_qkv(const u16* __restrict__ A, const u16* __restrict__ Bw,
              u16* __restrict__ qb, u16* __restrict__ kb, u16* __restrict__ vtb,
              u16* __restrict__ kwt, const float2* __restrict__ rtab) {
  __shared__ __align__(16) u16 smem[65536];   // 128 KB: 2 bufs x 64 KB
  const int tid = threadIdx.x;
  const int w = tid >> 6, lane = tid & 63;    // 8 waves
  const int quad = lane >> 4, l15 = lane & 15;
  const int wr = w >> 2, wc = w & 3;
  const int m0 = blockIdx.y * 256, n0 = blockIdx.x * 256;
  constexpr int NT = 16;                      // K=1024 / BK=64
  const size_t tsz = (size_t)32 * 512;        // u16 per packed 16-row tile (K=1024)

  auto stageA = [&](int buf, int t, int half) {
    const int rt = (w & 3) + (w >> 2) * 8 + half * 4;  // {0-3,8-11} or {4-7,12-15}
    const u16* src = A + ((size_t)(m0 >> 4) + rt) * tsz + (size_t)(2 * t) * 512 + lane * 8;
    u16* dst = &smem[buf * 32768 + rt * 1024];
    gld16(src, dst);            // kk0
    gld16(src + 512, dst + 512);// kk1
  };
  auto stageB = [&](int buf, int t, int half) {
    const int ct = half * 8 + w;
    const u16* src = Bw + ((size_t)(n0 >> 4) + ct) * tsz + (size_t)(2 * t) * 512 + lane * 8;
    u16* dst = &smem[buf * 32768 + 16384 + ct * 1024];
    gld16(src, dst);
    gld16(src + 512, dst + 512);
  };

  floatx4 acc[8][4] = {};

  // prologue: tile 0 complete (4 units), tile 1 first 3 units (S_A1(1) in loop)
  stageB(0, 0, 0); stageB(0, 0, 1); stageA(0, 0, 0); stageA(0, 0, 1);
  stageB(1, 1, 0); stageB(1, 1, 1); stageA(1, 1, 0);
  asm volatile("s_waitcnt vmcnt(6)" ::: "memory");   // tile 0 landed; 3 units in flight
  __builtin_amdgcn_s_barrier();

  for (int t = 0; t < NT; ++t) {
    const int bb = (t & 1) * 32768;
    const u16* Ap = &smem[bb];
    const u16* Bp = &smem[bb + 16384];
    short8 b[4][2];
#pragma unroll
    for (int j = 0; j < 4; ++j)
#pragma unroll
      for (int kk = 0; kk < 2; ++kk)
        b[j][kk] = *(const short8*)&Bp[((wc * 4 + j) * 2 + kk) * 512 + lane * 8];
#pragma unroll
    for (int q = 0; q < 4; ++q) {
      short8 a[2][2];
#pragma unroll
      for (int i = 0; i < 2; ++i)
#pragma unroll
        for (int kk = 0; kk < 2; ++kk)
          a[i][kk] =
              *(const short8*)&Ap[((wr * 8 + q * 2 + i) * 2 + kk) * 512 + lane * 8];
      if (q == 0) {
        if (t + 1 < NT) stageA((t + 1) & 1, t + 1, 1);       // S_A1(t+1)
      } else if (q == 1) {
        if (t + 2 < NT) stageB(t & 1, t + 2, 0);             // S_B0(t+2)
      } else if (q == 2) {
        if (t + 2 < NT) stageB(t & 1, t + 2, 1);             // S_B1(t+2)
      } else {
        if (t + 2 < NT) stageA(t & 1, t + 2, 0);             // S_A0(t+2)
        if (t <= NT - 3)
          asm volatile("s_waitcnt vmcnt(6)" ::: "memory");   // tile t+1 landed
        else
          asm volatile("s_waitcnt vmcnt(0)" ::: "memory");
      }
      __builtin_amdgcn_s_barrier();                          // BAR1
      asm volatile("s_waitcnt lgkmcnt(0)" ::: "memory");
      __builtin_amdgcn_sched_barrier(0);                     // rule #18
      __builtin_amdgcn_s_setprio(1);
#pragma unroll
      for (int i = 0; i < 2; ++i)
#pragma unroll
        for (int j = 0; j < 4; ++j)
#pragma unroll
          for (int kk = 0; kk < 2; ++kk)
            acc[q * 2 + i][j] = mfma16(a[i][kk], b[j][kk], acc[q * 2 + i][j]);
      __builtin_amdgcn_s_setprio(0);
      asm volatile("" ::: "memory");
      __builtin_amdgcn_s_barrier();                          // BAR2
      asm volatile("" ::: "memory");
    }
  }

  // staging LDS dead -> 8 KB wave-private scratch (8 waves x 8 KB = 64 KB)
  u16* scr = &smem[w * 4096];
  const int ncb = n0 + wc * 64;
  const int which = n0 >> 10;         // 0:q 1:k 2:v
  const int hh = (ncb & 1023) >> 6;   // head within matrix

#pragma unroll
  for (int ih = 0; ih < 2; ++ih) {
    const int mrb = m0 + wr * 128 + ih * 64;
    const int bidx = mrb >> 11;
    const int seq0 = mrb & 2047;
    const int chk = seq0 >> 7;        // 128-seq chunk; in-chunk half = ih

    if (which < 2) {
      // ---- pass 1: q/k, RoPE applied, rotated d-chunks in scr [sl][d-rot]
#pragma unroll
      for (int j = 0; j < 4; ++j) {
        const int d = j * 16 + l15;
        const int dc = d >> 3, dl = d & 7;
#pragma unroll
        for (int i = 0; i < 4; ++i)
#pragma unroll
          for (int r = 0; r < 4; ++r) {
            const int sl = i * 16 + quad * 4 + r;
            const int seq = seq0 + sl;
            const float v = acc[ih * 4 + i][j][r];
            const float p = __shfl_xor(v, 1, 64);
            const float2 sc = rtab[(d >> 1) + seq * 32];
            const float res = (d & 1) ? (v * sc.y + p * sc.x) : (v * sc.y - p * sc.x);
            scr[sl * 64 + (((dc + (sl >> 2)) & 7) << 3) + dl] = f2bf(res);
          }
      }
      u16* dst = ((which == 0) ? qb : kb) +
                 (((size_t)(bidx * 16 + hh) * 16 + chk) << 13);
#pragma unroll
      for (int nl = 0; nl < 4; ++nl)
#pragma unroll
        for (int kk2 = 0; kk2 < 2; ++kk2) {
          const int slr = nl * 16 + l15;
          const int slot = ((kk2 * 4 + quad) + (slr >> 2)) & 7;
          short8 vv = *(const short8*)&scr[slr * 64 + slot * 8];
          *(short8*)(dst + (((ih * 4 + nl) * 2 + kk2) * 512) + lane * 8) = vv;
        }
      if (which == 1) {
        // ---- pass 2: kwt panes, decay-weighted transpose
        const float l2h = __log2f(1.0f - exp2f(-(float)(5 + hh)));
#pragma unroll
        for (int j = 0; j < 4; ++j) {
          const int d = j * 16 + l15;
#pragma unroll
          for (int i = 0; i < 4; ++i) {
            ushort4 pk;
#pragma unroll
            for (int r = 0; r < 4; ++r) {
              const int sl = i * 16 + quad * 4 + r;
              const int seq = seq0 + sl;
              const float v = acc[ih * 4 + i][j][r];
              const float p = __shfl_xor(v, 1, 64);
              const float2 sc = rtab[(d >> 1) + seq * 32];
              const float res = (d & 1) ? (v * sc.y + p * sc.x) : (v * sc.y - p * sc.x);
              const float wgt = exp2f((float)(127 - (seq & 127)) * l2h);
              ((u16*)&pk)[r] = f2bf(res * wgt);
            }
            *(ushort4*)&scr[d * 64 + ((i * 16 + quad * 4 + 8 * (d & 7)) & 63)] = pk;
          }
        }
        u16* dw = kwt + (((size_t)(bidx * 16 + hh) * 16 + chk) << 13);
#pragma unroll
        for (int m = 0; m < 4; ++m)
#pragma unroll
          for (int ks2 = 0; ks2 < 2; ++ks2) {
            const int dr = m * 16 + l15;
            const int col = ((ks2 * 32 + quad * 8) + 8 * (dr & 7)) & 63;
            short8 vv = *(const short8*)&scr[dr * 64 + col];
            *(short8*)(dw + ((m * 4 + ih * 2 + ks2) * 512) + lane * 8) = vv;
          }
      }
    } else {
      // ---- v transposed panes
#pragma unroll
      for (int j = 0; j < 4; ++j) {
        const int d = j * 16 + l15;
#pragma unroll
        for (int i = 0; i < 4; ++i) {
          ushort4 pk;
          pk.x = f2bf(acc[ih * 4 + i][j][0]);
          pk.y = f2bf(acc[ih * 4 + i][j][1]);
          pk.z = f2bf(acc[ih * 4 + i][j][2]);
          pk.w = f2bf(acc[ih * 4 + i][j][3]);
          *(ushort4*)&scr[d * 64 + ((i * 16 + quad * 4 + 8 * (d & 7)) & 63)] = pk;
        }
      }
      u16* dh = vtb + (((size_t)(bidx * 16 + hh) * 16 + chk) << 13);
#pragma unroll
      for (int m = 0; m < 4; ++m)
#pragma unroll
        for (int ks2 = 0; ks2 < 2; ++ks2) {
          const int dr = m * 16 + l15;
          const int col = ((ks2 * 32 + quad * 8) + 8 * (dr & 7)) & 63;
          short8 vv = *(const short8*)&scr[dr * 64 + col];
          *(short8*)(dh + ((m * 4 + ih * 2 + ks2) * 512) + lane * 8) = vv;
        }
    }
  }
}

// ---------------------------------------------------------------- out GEMM (r9 structure)
// N=1024 too small for the 256^2 grid -> keep the proven BM=64 2-phase loop.
template <int EPI>
__global__ __launch_bounds__(256, 2)
void gemm_bt(const u16* __restrict__ A, const u16* __restrict__ Bw, int K,
             const float2* __restrict__ rtab, float* __restrict__ outp) {
  constexpr int AP   = 4;                         // A panes per buffer
  constexpr int BUFU = (AP + 16) * 512;           // u16 per buffer
  constexpr int AOFF = AP * 512;                  // B area offset in buffer
  constexpr int AI   = 4;                         // acc rows (16-row frags)
  __shared__ __align__(16) u16 smem[3 * 12288];
  const int tid = threadIdx.x;
  const int w = tid >> 6, lane = tid & 63;        // 4 waves
  const int quad = lane >> 4, l15 = lane & 15;
  const int m0 = blockIdx.y * 64, n0 = blockIdx.x * 256;

  const size_t tsz = (size_t)(K >> 5) * 512;
  const u16* A0 = A + ((size_t)(m0 >> 4) + w) * tsz + lane * 8;
  const u16* Bb = Bw + ((size_t)(n0 >> 4) + 4 * w) * tsz + lane * 8;

  auto stage = [&](int buf, int kc) {
    const int nb = buf * BUFU;
    gld16(A0 + (size_t)kc * 512, &smem[nb + w * 512]);
#pragma unroll
    for (int e = 0; e < 4; ++e)
      gld16(Bb + (size_t)e * tsz + (size_t)kc * 512,
            &smem[nb + AOFF + (4 * w + e) * 512]);
  };

  floatx4 acc[AI][4] = {};
  const int NT = K >> 5;

  stage(0, 0);
  stage(1, 1);
  asm volatile("s_waitcnt vmcnt(5)" ::: "memory");
  __builtin_amdgcn_s_barrier();

  int cur = 0, stg = 2;
  for (int t = 0; t < NT; ++t) {
    const u16* Ap = &smem[cur * BUFU];
    const u16* Bp = Ap + AOFF;
    short8 a[AI], b[4];
#pragma unroll
    for (int i = 0; i < AI; ++i)
      a[i] = *(const short8*)&Ap[i * 512 + lane * 8];
#pragma unroll
    for (int j = 0; j < 4; ++j)
      b[j] = *(const short8*)&Bp[(w * 4 + j) * 512 + lane * 8];
    if (t + 2 < NT) {
      stage(stg, t + 2);
      asm volatile("s_waitcnt vmcnt(5)" ::: "memory");
    } else {
      asm volatile("s_waitcnt vmcnt(0)" ::: "memory");
    }
    __builtin_amdgcn_s_barrier();
    asm volatile("s_waitcnt lgkmcnt(0)" ::: "memory");
    __builtin_amdgcn_sched_barrier(0);
    __builtin_amdgcn_s_setprio(1);
#pragma unroll
    for (int i = 0; i < AI; ++i)
#pragma unroll
      for (int j = 0; j < 4; ++j)
        acc[i][j] = mfma16(a[i], b[j], acc[i][j]);
    __builtin_amdgcn_s_setprio(0);
    asm volatile("" ::: "memory");
    __builtin_amdgcn_s_barrier();
    asm volatile("" ::: "memory");
    cur = (cur == 2) ? 0 : cur + 1;
    stg = (stg == 2) ? 0 : stg + 1;
  }

  u16* scr = &smem[w * 4096];
  const int ncb = n0 + w * 64;
  const int mrb = m0;
  // ---- fp32 out via LDS quarter-tiles (16 rows x pitch 65), full-line stores
  float* scrf = (float*)scr;
  const int lr4 = lane >> 4, lc16 = lane & 15;
#pragma unroll
  for (int p = 0; p < 4; ++p) {
#pragma unroll
    for (int j = 0; j < 4; ++j)
#pragma unroll
      for (int r = 0; r < 4; ++r)
        scrf[(quad * 4 + r) * 65 + j * 16 + l15] = acc[p][j][r];
#pragma unroll
    for (int cch = 0; cch < 4; ++cch) {
      const int rr = cch * 4 + lr4;
      float4 vv = *(const float4*)&scrf[rr * 65 + lc16 * 4];
      *(float4*)&outp[(size_t)(mrb + p * 16 + rr) * 1024 + ncb + lc16 * 4] = vv;
    }
  }
}

// ---------------------------------------------------------------- fused KV-chunk + scan
__global__ __launch_bounds__(256, 2)
void kvscan_kernel(const u16* __restrict__ kwt, const u16* __restrict__ vtb,
                   u16* __restrict__ Sb) {
  __shared__ __align__(16) u16 kls[2][16 * 512];   // 32 KB
  __shared__ __align__(16) u16 vls[2][16 * 512];   // 32 KB
  const int bh = blockIdx.x;
  const int tid = threadIdx.x, w = tid >> 6, lane = tid & 63;
  const int quad = lane >> 4, l15 = lane & 15;
  const int h = bh & 15;
  const float l2 = __log2f(1.0f - exp2f(-(float)(5 + h)));
  const float lamL = exp2f(128.0f * l2);

  const u16* kg = kwt + ((size_t)bh << 17);
  const u16* vg = vtb + ((size_t)bh << 17);
  u16* sbase = Sb + ((size_t)bh << 16);

  auto stage = [&](int buf, int c) {
    const u16* kc = kg + ((size_t)c << 13);
    const u16* vc = vg + ((size_t)c << 13);
#pragma unroll
    for (int rg = 0; rg < 4; ++rg) {
      const int rid = w * 4 + rg;
      gld16(kc + rid * 512 + lane * 8, &kls[buf][rid * 512]);
      gld16(vc + rid * 512 + lane * 8, &vls[buf][rid * 512]);
    }
  };

  float S[4][4] = {};   // S[m][r]: dk = m*16+quad*4+r, dv = w*16+l15

  stage(0, 0);
  int buf = 0;
  for (int c = 0; c < 16; ++c) {
    if (c + 1 < 16) {
      stage(buf ^ 1, c + 1);
      asm volatile("s_waitcnt vmcnt(8)" ::: "memory");
    } else {
      asm volatile("s_waitcnt vmcnt(0)" ::: "memory");
    }
    __builtin_amdgcn_s_barrier();
    asm volatile("" ::: "memory");

    u16* sp = sbase + ((size_t)c << 12);
#pragma unroll
    for (int m = 0; m < 4; ++m) {
      ushort4 pk;
#pragma unroll
      for (int r = 0; r < 4; ++r) ((u16*)&pk)[r] = f2bf(S[m][r]);
      const int lanep = ((m & 1) * 2 + (quad >> 1)) * 16 + l15;
      *(ushort4*)(sp + (w * 2 + (m >> 1)) * 512 + lanep * 8 + (quad & 1) * 4) = pk;
    }

    floatx4 acc[4] = {};
#pragma unroll
    for (int kst = 0; kst < 4; ++kst) {
      short8 bf = *(const short8*)&vls[buf][(w * 4 + kst) * 512 + lane * 8];
#pragma unroll
      for (int m = 0; m < 4; ++m) {
        short8 af = *(const short8*)&kls[buf][(m * 4 + kst) * 512 + lane * 8];
        acc[m] = mfma16(af, bf, acc[m]);
      }
    }
#pragma unroll
    for (int m = 0; m < 4; ++m)
#pragma unroll
      for (int r = 0; r < 4; ++r)
        S[m][r] = lamL * S[m][r] + acc[m][r];

    asm volatile("" ::: "memory");
    __builtin_amdgcn_s_barrier();
    buf ^= 1;
  }
}

// ---------------------------------------------------------------- chunked attention
__global__ __launch_bounds__(256, 2)
void attn_chunk_kernel(const u16* __restrict__ qb, const u16* __restrict__ kb,
                       const u16* __restrict__ vtb, const u16* __restrict__ Sb,
                       const float* __restrict__ lnw, const float* __restrict__ lnb,
                       u16* __restrict__ yb) {
  __shared__ __align__(16) u16 kls[16 * 512];
  __shared__ __align__(16) u16 vls[16 * 512];
  __shared__ __align__(16) u16 Sls[8 * 512];
  __shared__ __align__(16) u16 pls[4 * 32 * 40];   // per-wave quarter P strip, pitch 40

  const int c = blockIdx.x, bh = blockIdx.y, h = bh & 15;
  const int tid = threadIdx.x;
  const int w = tid >> 6, lane = tid & 63, quad = lane >> 4, l15 = lane & 15;
  const float l2 = __log2f(1.0f - exp2f(-(float)(5 + h)));

  const u16* kg = kb + (((size_t)bh * 16 + c) << 13);
  const u16* vg = vtb + (((size_t)bh * 16 + c) << 13);
  const u16* Sg = Sb + (((size_t)bh * 16 + c) << 12);
#pragma unroll
  for (int rg = 0; rg < 4; ++rg) {
    const int kid = w * 4 + rg;
    gld16(kg + kid * 512 + lane * 8, &kls[kid * 512]);
    gld16(vg + kid * 512 + lane * 8, &vls[kid * 512]);
  }
#pragma unroll
  for (int e = 0; e < 2; ++e) {
    const int rid = w * 2 + e;
    gld16(Sg + rid * 512 + lane * 8, &Sls[rid * 512]);
  }

  short8 qf[2][2];
  {
    const u16* qp = qb + (((size_t)bh * 16 + c) << 13);
#pragma unroll
    for (int i = 0; i < 2; ++i)
#pragma unroll
      for (int kk = 0; kk < 2; ++kk)
        qf[i][kk] = *(const short8*)(qp + (((w * 2 + i) * 2 + kk) * 512) + lane * 8);
  }
  float lnwv[4], lnbv[4];
#pragma unroll
  for (int jd = 0; jd < 4; ++jd) {
    lnwv[jd] = lnw[jd * 16 + l15];
    lnbv[jd] = lnb[jd * 16 + l15];
  }
  __syncthreads();

  floatx4 sacc[2][8] = {};
#pragma unroll
  for (int kk = 0; kk < 2; ++kk) {
    short8 bf[8];
#pragma unroll
    for (int j = 0; j < 8; ++j)
      bf[j] = *(const short8*)&kls[(j * 2 + kk) * 512 + lane * 8];
#pragma unroll
    for (int i = 0; i < 2; ++i)
#pragma unroll
      for (int j = 0; j < 8; ++j)
        sacc[i][j] = mfma16(qf[i][kk], bf[j], sacc[i][j]);
  }

  floatx4 oacc[2][4] = {};
#pragma unroll
  for (int kk = 0; kk < 2; ++kk)
#pragma unroll
    for (int nd = 0; nd < 4; ++nd) {
      short8 sf = *(const short8*)&Sls[(nd * 2 + kk) * 512 + lane * 8];
#pragma unroll
      for (int i = 0; i < 2; ++i)
        oacc[i][nd] = mfma16(qf[i][kk], sf, oacc[i][nd]);
    }
  float rowf[8];
#pragma unroll
  for (int i = 0; i < 2; ++i)
#pragma unroll
    for (int r = 0; r < 4; ++r)
      rowf[i * 4 + r] = exp2f((float)(w * 32 + i * 16 + quad * 4 + r) * l2);
  const float lam1 = exp2f(l2);
#pragma unroll
  for (int i = 0; i < 2; ++i)
#pragma unroll
    for (int nd = 0; nd < 4; ++nd)
#pragma unroll
      for (int r = 0; r < 4; ++r)
        oacc[i][nd][r] *= rowf[i * 4 + r] * lam1;

  float colf[8];
#pragma unroll
  for (int j = 0; j < 8; ++j) colf[j] = exp2f(-(float)(j * 16 + l15) * l2);
  u16* pw = &pls[w * 1280];
#pragma unroll
  for (int kst = 0; kst < 4; ++kst) {
#pragma unroll
    for (int jl = 0; jl < 2; ++jl) {
      const int j = kst * 2 + jl;
#pragma unroll
      for (int i = 0; i < 2; ++i)
#pragma unroll
        for (int r = 0; r < 4; ++r) {
          const int srow = i * 16 + quad * 4 + r;
          const int dlt = (w * 32 + srow) - (j * 16 + l15);
          const float v =
              (dlt >= 0) ? sacc[i][j][r] * rowf[i * 4 + r] * colf[j] : 0.0f;
          pw[srow * 40 + jl * 16 + l15] = f2bf(v);
        }
    }
    short8 pf[2], vf[4];
#pragma unroll
    for (int i = 0; i < 2; ++i)
      pf[i] = *(const short8*)&pw[(i * 16 + l15) * 40 + quad * 8];
#pragma unroll
    for (int jd = 0; jd < 4; ++jd)
      vf[jd] = *(const short8*)&vls[(jd * 4 + kst) * 512 + lane * 8];
#pragma unroll
    for (int i = 0; i < 2; ++i)
#pragma unroll
      for (int jd = 0; jd < 4; ++jd)
        oacc[i][jd] = mfma16(pf[i], vf[jd], oacc[i][jd]);
  }

  __syncthreads();
  u16* scrw = &kls[w * 2048];
  const int b = bh >> 4;
#pragma unroll
  for (int i = 0; i < 2; ++i)
#pragma unroll
    for (int r = 0; r < 4; ++r) {
      float sum = 0.f, ssq = 0.f;
#pragma unroll
      for (int jd = 0; jd < 4; ++jd) {
        const float v = oacc[i][jd][r];
        sum += v;
        ssq += v * v;
      }
#pragma unroll
      for (int off = 1; off < 16; off <<= 1) {
        sum += __shfl_xor(sum, off, 64);
        ssq += __shfl_xor(ssq, off, 64);
      }
      const float mu = sum * (1.0f / 64.0f);
      const float var = ssq * (1.0f / 64.0f) - mu * mu;
      const float rst = rsqrtf(var + 1e-5f);
      const int sl = i * 16 + quad * 4 + r;
#pragma unroll
      for (int jd = 0; jd < 4; ++jd) {
        const float z = (oacc[i][jd][r] - mu) * rst * lnwv[jd] + lnbv[jd];
        const float y = z / (1.0f + expf(-z));   // SiLU
        const int f = jd * 16 + l15;
        scrw[sl * 64 + ((((f >> 3) + (sl >> 2)) & 7) << 3) + (f & 7)] = f2bf(y);
      }
    }
  const int tile0 = b * 128 + c * 8 + w * 2;
#pragma unroll
  for (int tt = 0; tt < 2; ++tt)
#pragma unroll
    for (int kcl = 0; kcl < 2; ++kcl) {
      const int row = tt * 16 + l15;
      const int slot = ((kcl * 4 + quad) + (row >> 2)) & 7;
      short8 vv = *(const short8*)&scrw[row * 64 + slot * 8];
      *(short8*)(yb + ((size_t)(tile0 + tt) * 32 + h * 2 + kcl) * 512 + lane * 8) = vv;
    }
}

// ---------------------------------------------------------------- launch
extern "C" void kernel_launch(void* const* d_in, const int* in_sizes, int n_in,
                              void* d_out, int out_size, void* d_ws, size_t ws_size,
                              hipStream_t stream) {
  const float* x   = (const float*)d_in[0];
  const float* Wq  = (const float*)d_in[1];
  const float* Wk  = (const float*)d_in[2];
  const float* Wv  = (const float*)d_in[3];
  const float* Wo  = (const float*)d_in[4];
  const float* lnw = (const float*)d_in[5];
  const float* lnb = (const float*)d_in[6];
  float* out = (float*)d_out;

  char* ws = (char*)d_ws;
  u16* xbf  = (u16*)(ws + 0);         // 16 MB pane-packed x; reused as packed y
  u16* wqkv = (u16*)(ws + 16777216);  // 6 MB pane-packed — dead after QKV gemm
  u16* Sb   = (u16*)(ws + 16777216);  // 8 MB S panes — written after wqkv dead
  u16* qbuf = (u16*)(ws + 25165824);  // 16 MB q panes
  u16* kbuf = (u16*)(ws + 41943040);  // 16 MB k panes
  u16* vtb  = (u16*)(ws + 58720256);  // 16 MB v^T panes
  u16* wo   = (u16*)(ws + 75497472);  // 2 MB pane-packed
  float2* rtab = (float2*)(ws + 77594624);  // 512 KB
  u16* yb   = xbf;
  u16* kwt  = (u16*)d_out;                          // 16 MB kwt panes (scratch)

  prep_kernel<<<dim3(1024), dim3(256), 0, stream>>>(x, Wq, Wk, Wv, Wo, xbf, wqkv, wo,
                                                    rtab);
  gemm_qkv<<<dim3(12, 32), dim3(512), 0, stream>>>(xbf, wqkv, qbuf, kbuf, vtb, kwt,
                                                   rtab);
  kvscan_kernel<<<dim3(64), dim3(256), 0, stream>>>(kwt, vtb, Sb);
  attn_chunk_kernel<<<dim3(16, 64), dim3(256), 0, stream>>>(qbuf, kbuf, vtb, Sb, lnw,
                                                            lnb, yb);
  gemm_bt<1><<<dim3(4, 128), dim3(256), 0, stream>>>(yb, wo, 1024, rtab, out);
}